// Round 1
// baseline (120.773 us; speedup 1.0000x reference)
//
#include <hip/hip_runtime.h>

// FwFM second-order interaction, single fused kernel.
// Identity: v^T S v == v^T W v for S = 0.5(W+W^T), diag(S) = diag(W), so
//   out[b,d] = sum_{k<l} 0.5*(W[k,l]+W[l,k]) * x[k,b,d]*x[l,b,d]   (741 pairs, K=39)
//
// Shapes: x [39, 8192, 64] f32, W [39,39] f32, out [8192,64] f32.
// Memory-bound: ~84 MB traffic -> ~13.3 us floor at 6.3 TB/s achievable.
//
// R3 changes vs R2 (117.1 us):
//  - Coefficient symmetrization fused into the main kernel (was a separate
//    7-block kernel + graph dependency edge = ~3-5 us of serialization).
//    Each block recomputes the 741 coefs into LDS: 6 W-loads/thread issued
//    BEFORE the 39 x-loads (oldest vmcnt slots -> drain first, work hides
//    under x-load latency), then one __syncthreads.
//  - Inner loop coefficient operand moves SGPR -> LDS broadcast read
//    (wave-uniform address, conflict-free). ~741 ds_read slots/wave ~= 5k
//    LDS-pipe cycles, hidden under ~31k memory cycles/SIMD-round.
//  - W L2 traffic: 1024 blocks x 6 KB = 6 MB, fully L2-resident. Trivial.

#define KF 39
#define KK (KF * KF)                 // 1521
#define NPAIR (KF * (KF - 1) / 2)   // 741
#define NELEM (8192 * 64)            // B*D = 524288 output elements
#define NV2   (NELEM / 2)            // float2 elements per field = 262144
#define COEF_ITER 6                  // ceil(1521 / 256)

__global__ __attribute__((amdgpu_flat_work_group_size(256, 256), amdgpu_waves_per_eu(4, 5)))
void fwfm_kernel(const float* __restrict__ x,
                 const float* __restrict__ W,
                 float* __restrict__ out) {
    const int tid = threadIdx.x;
    const int n = blockIdx.x * 256 + tid;   // float2 index in [0, NV2)

    const float2* __restrict__ x2 = reinterpret_cast<const float2*>(x);

    __shared__ float cs[NPAIR];

    // ---- Phase 0: issue W loads (oldest vmcnt entries, retire first) ----
    // Thread t covers W-matrix cells t, t+256, ..., t+1280 (6 cells; last
    // partial). Invalid cells clamp to 0 (harmless duplicate load of W[0]).
    float wa[COEF_ITER], wb[COEF_ITER];
    int   off[COEF_ITER];
#pragma unroll
    for (int i = 0; i < COEF_ITER; ++i) {
        const int  t  = tid + i * 256;
        const bool in = (t < KK);
        const int  tc = in ? t : 0;
        const int  k  = tc / KF;            // magic-mul, no divide
        const int  l  = tc - k * KF;
        off[i] = (in && l < k) ? (k * (k - 1)) / 2 + l : -1;
        wa[i] = W[tc];                      // W[k,l]
        wb[i] = W[l * KF + k];              // W[l,k]
    }

    // ---- Phase 1: issue the 39 coalesced dwordx2 x-loads ----
    float2 v[KF];
#pragma unroll
    for (int k = 0; k < KF; ++k) {
        v[k] = x2[(size_t)k * NV2 + n];
    }

    // ---- Phase 2: symmetrize into LDS (0.5 folded in), barrier ----
#pragma unroll
    for (int i = 0; i < COEF_ITER; ++i) {
        if (off[i] >= 0) {
            cs[off[i]] = 0.5f * (wa[i] + wb[i]);
        }
    }
    __syncthreads();

    // ---- Phase 3: pair loop in coefficient order (p sequential) ----
    // cs[p] is wave-uniform -> LDS broadcast, no bank conflict.
    // Two chains (x,y) for ILP; 0.5 already folded into cs.
    float accx = 0.0f, accy = 0.0f;
    int p = 0;
#pragma unroll
    for (int k = 1; k < KF; ++k) {
        float wx = 0.0f, wy = 0.0f;
#pragma unroll
        for (int l = 0; l < k; ++l) {
            const float cc = cs[p++];
            wx = fmaf(cc, v[l].x, wx);
            wy = fmaf(cc, v[l].y, wy);
        }
        accx = fmaf(v[k].x, wx, accx);
        accy = fmaf(v[k].y, wy, accy);
    }

    float2 o;
    o.x = accx;
    o.y = accy;
    reinterpret_cast<float2*>(out)[n] = o;
}

extern "C" void kernel_launch(void* const* d_in, const int* in_sizes, int n_in,
                              void* d_out, int out_size, void* d_ws, size_t ws_size,
                              hipStream_t stream) {
    const float* x = (const float*)d_in[0];          // [39, 8192, 64]
    const float* W = (const float*)d_in[1];          // [39, 39]
    float* out = (float*)d_out;                      // [8192, 64]
    (void)d_ws; (void)ws_size;                       // workspace no longer needed

    fwfm_kernel<<<NV2 / 256, 256, 0, stream>>>(x, W, out);
}

// Round 2
// 117.232 us; speedup vs baseline: 1.0302x; 1.0302x over previous
//
#include <hip/hip_runtime.h>

// FwFM second-order interaction, single fused kernel.
// Identity: v^T S v == v^T W v for S = 0.5(W+W^T), diag(S) = diag(W), so
//   out[b,d] = sum_{k<l} 0.5*(W[k,l]+W[l,k]) * x[k,b,d]*x[l,b,d]   (741 pairs, K=39)
//
// Shapes: x [39, 8192, 64] f32, W [39,39] f32, out [8192,64] f32.
// Memory-bound: ~84 MB traffic -> ~13 us floor at 6.5 TB/s achievable.
//
// R4 changes vs R3 (120.8 us total; kernel ~19 us of it, rest = 2 harness
// poison-fills @ ~50 us that we cannot control):
//  - float2 -> float4 per-thread (16 B/lane loads, G13 sweet spot): halves
//    vector-memory instruction count per byte. Kernel was at ~4.4 TB/s vs
//    6.5 TB/s proven achievable on this box by the harness fills.
//  - VGPR: v[39] float4 = 156 + ~35 overhead ~= 190 -> waves_per_eu(2,4)
//    (256-VGPR budget, no spill). In-flight bytes/CU = 8 waves x 64 x 39 x
//    16 B ~= 319 KB >> ~9 KB BW*latency product -> 2 waves/EU suffices since
//    all 39 loads issue before first use.
//  - Grid: 512 blocks = exactly 2 blocks/CU, no tail.

#define KF 39
#define KK (KF * KF)                 // 1521
#define NPAIR (KF * (KF - 1) / 2)   // 741
#define NELEM (8192 * 64)            // B*D = 524288 output elements
#define NV4   (NELEM / 4)            // float4 elements per field = 131072
#define COEF_ITER 6                  // ceil(1521 / 256)

__global__ __attribute__((amdgpu_flat_work_group_size(256, 256), amdgpu_waves_per_eu(2, 4)))
void fwfm_kernel(const float* __restrict__ x,
                 const float* __restrict__ W,
                 float* __restrict__ out) {
    const int tid = threadIdx.x;
    const int n = blockIdx.x * 256 + tid;   // float4 index in [0, NV4)

    const float4* __restrict__ x4 = reinterpret_cast<const float4*>(x);

    __shared__ float cs[NPAIR];

    // ---- Phase 0: issue W loads (oldest vmcnt entries, retire first) ----
    float wa[COEF_ITER], wb[COEF_ITER];
    int   off[COEF_ITER];
#pragma unroll
    for (int i = 0; i < COEF_ITER; ++i) {
        const int  t  = tid + i * 256;
        const bool in = (t < KK);
        const int  tc = in ? t : 0;
        const int  k  = tc / KF;            // magic-mul, no divide
        const int  l  = tc - k * KF;
        off[i] = (in && l < k) ? (k * (k - 1)) / 2 + l : -1;
        wa[i] = W[tc];                      // W[k,l]
        wb[i] = W[l * KF + k];              // W[l,k]
    }

    // ---- Phase 1: issue the 39 coalesced dwordx4 x-loads ----
    float4 v[KF];
#pragma unroll
    for (int k = 0; k < KF; ++k) {
        v[k] = x4[(size_t)k * NV4 + n];
    }

    // ---- Phase 2: symmetrize into LDS (0.5 folded in), barrier ----
#pragma unroll
    for (int i = 0; i < COEF_ITER; ++i) {
        if (off[i] >= 0) {
            cs[off[i]] = 0.5f * (wa[i] + wb[i]);
        }
    }
    __syncthreads();

    // ---- Phase 3: pair loop in coefficient order (p sequential) ----
    // cs[p] is wave-uniform -> LDS broadcast, no bank conflict; consecutive
    // unrolled reads merge into ds_read_b128. Four FMA chains for ILP.
    float accx = 0.0f, accy = 0.0f, accz = 0.0f, accw = 0.0f;
    int p = 0;
#pragma unroll
    for (int k = 1; k < KF; ++k) {
        float wx = 0.0f, wy = 0.0f, wz = 0.0f, ww = 0.0f;
#pragma unroll
        for (int l = 0; l < k; ++l) {
            const float cc = cs[p++];
            wx = fmaf(cc, v[l].x, wx);
            wy = fmaf(cc, v[l].y, wy);
            wz = fmaf(cc, v[l].z, wz);
            ww = fmaf(cc, v[l].w, ww);
        }
        accx = fmaf(v[k].x, wx, accx);
        accy = fmaf(v[k].y, wy, accy);
        accz = fmaf(v[k].z, wz, accz);
        accw = fmaf(v[k].w, ww, accw);
    }

    float4 o;
    o.x = accx;   // 0.5 already folded into cs
    o.y = accy;
    o.z = accz;
    o.w = accw;
    reinterpret_cast<float4*>(out)[n] = o;
}

extern "C" void kernel_launch(void* const* d_in, const int* in_sizes, int n_in,
                              void* d_out, int out_size, void* d_ws, size_t ws_size,
                              hipStream_t stream) {
    const float* x = (const float*)d_in[0];          // [39, 8192, 64]
    const float* W = (const float*)d_in[1];          // [39, 39]
    float* out = (float*)d_out;                      // [8192, 64]
    (void)d_ws; (void)ws_size;                       // workspace unused

    fwfm_kernel<<<NV4 / 256, 256, 0, stream>>>(x, W, out);
}